// Round 10
// baseline (225.279 us; speedup 1.0000x reference)
//
#include <hip/hip_runtime.h>
#include <hip/hip_bf16.h>

typedef unsigned short u16;
typedef unsigned int u32;
typedef unsigned long long u64;
typedef short bf16x8 __attribute__((ext_vector_type(8)));
typedef float f32x4  __attribute__((ext_vector_type(4)));

// RowLSTM B=32, Cin=3, H=W=64, HC=128, gates o,f,i,g (all sigmoid), c=f*c+i*g,
// h=o*tanh(c). Masked-B 1x3 conv: taps (w-1, w).
//
// Round 17: GATE-SPLIT WAVE PAIRS -- 1024 threads, 16 waves, 4 waves/SIMD.
// Diagnosis (r7..r9): latency-bound at 2 waves/SIMD; per-SIMD issue ~1400cy
// over a ~900cy serial chain; instruction diets now <3% each. Fix: wave pair
// (p, p+8) per hc-tile p. Front p: gates o,f (18 MFMA) + recurrence EW + all
// h/halo/out writes. Back p+8: gates i,g (18 MFMA) + ig=sig(i)*sig(g)
// (12 trans) shipped 16B/thread via LDS with a monotone per-pair flag (wdone
// protocol; single-buffered -- row barrier orders read[r] < write[r+1]).
// MFMA cycles unchanged (no N/M waste), trans rebalanced 24/12, issue streams
// 2->4 per SIMD. Math bit-identical to r9 (same fma/rcp forms, other wave).
// Everything else = r9: x_pk precompute, inverted-word halo (2MB ws, memset
// per launch), relaxed lgkmcnt-only barrier, capped spins, cvt_pk packing.

__device__ __forceinline__ u16 f2b(float f) {
    return __builtin_bit_cast(u16, __float2bfloat16(f));
}

#define LINE(kt, lane) (((kt) * 64 + (lane)) * 16)
#define BUFBYTES (8 * 64 * 16)   /* 8192 B per buffer (tiles 0..7) */
#define SPIN_CAP (1 << 16)

__global__ __launch_bounds__(1024, 1) void rowlstm_mfma14(
    const float* __restrict__ x,   const float* __restrict__ Wis,
    const float* __restrict__ bis, const float* __restrict__ Wss,
    const float* __restrict__ bss, const float* __restrict__ h0,
    const float* __restrict__ c0,  float* __restrict__ out,
    char* halo)
{
    __shared__ __align__(16) char lds_buf[2 * BUFBYTES];   // 16384 B
    __shared__ __align__(16) char lds_xpk[64 * 16 * 16];   // 16384 B (x K-tiles)
    __shared__ __align__(16) char lds_igb[8 * 64 * 16];    // 8192 B (ig handoff)
    __shared__ u16  lds_x[3 * 64 * 17];                    // 6528 B
    __shared__ float lds_bias[512];                        // 2048 B
    __shared__ u32  igf[8];                                // per-pair row flags

    const int tid  = threadIdx.x;
    const int s    = blockIdx.x;            // w-quarter
    const int b    = blockIdx.y;            // batch
    const int wid  = tid >> 6;              // wave [0,16)
    const int p    = wid & 7;               // hc-tile (pair id)
    const bool front = (wid < 8);           // front: gates o,f + recurrence
    const int lane = tid & 63;
    const int q    = lane >> 4;             // quad
    const int n    = lane & 15;             // w within quarter
    const int wbase = s * 16;

    // halo slot: per (b,s,r): 32 units x 8B = 256B; unit u holds ~[4xbf16 h]
    // for ic = u*4..u*4+3 of the right-edge column. word!=0 <=> valid.
    char* hs_my = halo + ((size_t)(b * 4 + s) * 64) * 256;
    char* hs_up = halo + ((size_t)(b * 4 + (s > 0 ? s - 1 : 0)) * 64) * 256;

    // ---------- phase 0: zero both B buffers + flags ----------
    if (tid < 1024)
        *(uint4*)(lds_buf + tid * 16) = make_uint4(0, 0, 0, 0);
    if (tid < 8) igf[tid] = 0;
    __syncthreads();

    // ---------- phase 1: one-time staging ----------
    if (tid < 512) lds_bias[tid] = bis[tid] + bss[tid];

    // x -> LDS bf16: [cch][r][wl1], wl1 = local w + 1 (col 0 = left halo col)
    for (int i = tid; i < 3264; i += 1024) {
        int cch = i / 1088, rem = i % 1088;
        int r = rem / 17, wl1 = rem % 17;
        int gw = wbase + wl1 - 1;
        lds_x[i] = (gw < 0) ? (u16)0
                 : f2b(x[(((size_t)b * 3 + cch) * 64 + r) * 64 + gw]);
    }

    // A-fragments: front waves hold gates 0,1 (o,f); back waves gates 2,3 (i,g)
    const int gbase = front ? 0 : 2;
    bf16x8 afr[2][9];
    {
        #pragma unroll
        for (int gg = 0; gg < 2; ++gg) {
            int oc = (gbase + gg) * 128 + p * 16 + n;  // m = n
            #pragma unroll
            for (int kt = 0; kt < 8; ++kt) {
                bf16x8 a;
                #pragma unroll
                for (int jj = 0; jj < 4; ++jj) {
                    int ic = kt * 16 + q * 4 + jj;
                    float2 wp = *(const float2*)&Wss[(size_t)(oc * 128 + ic) * 3];
                    a[jj]     = (short)f2b(wp.y);      // tap1 (center)
                    a[4 + jj] = (short)f2b(wp.x);      // tap0 (left)
                }
                afr[gg][kt] = a;
            }
            bf16x8 ax = {0, 0, 0, 0, 0, 0, 0, 0};
            if (q == 0) {
                #pragma unroll
                for (int cch = 0; cch < 3; ++cch) {
                    float2 wp = *(const float2*)&Wis[(size_t)(oc * 3 + cch) * 3];
                    ax[cch]     = (short)f2b(wp.y);
                    ax[4 + cch] = (short)f2b(wp.x);
                }
            }
            afr[gg][8] = ax;
        }
    }

    // c-state (front only) + h0 publish into buf0 (front waves own tiles)
    float cst[4] = {0, 0, 0, 0};
    if (front) {
        u16 hw[4];
        #pragma unroll
        for (int reg = 0; reg < 4; ++reg) {
            int hc = p * 16 + q * 4 + reg;
            int wg = wbase + n;
            cst[reg] = c0[hc * 64 + wg];
            hw[reg] = f2b(h0[hc * 64 + wg]);
        }
        u64 d01 = (u64)((u32)hw[0] | ((u32)hw[1] << 16))
                | ((u64)((u32)hw[2] | ((u32)hw[3] << 16)) << 32);
        *(u64*)(lds_buf + LINE(p, lane)) = d01;                 // tap1 halves
        int wl = n + 1;
        if (wl < 16)
            *(u64*)(lds_buf + LINE(p, q * 16 + wl) + 8) = d01;
    }
    // s>0: left-edge tap0 column from h0[:, wbase-1] (h0 is known globally)
    if (s > 0 && tid < 32) {
        int ic0 = tid * 4;
        u64 v = (u64)((u32)f2b(h0[(ic0 + 0) * 64 + wbase - 1]) | ((u32)f2b(h0[(ic0 + 1) * 64 + wbase - 1]) << 16))
              | ((u64)((u32)f2b(h0[(ic0 + 2) * 64 + wbase - 1]) | ((u32)f2b(h0[(ic0 + 3) * 64 + wbase - 1]) << 16)) << 32);
        *(u64*)(lds_buf + LINE(tid >> 2, (tid & 3) * 16) + 8) = v;
    }

    // ensure lds_x fully written before packing x_pk
    __syncthreads();

    // x_pk[r][n] 16B = packed x K-tile value for (row r, col n); 1024 slots
    {
        int slot = tid;
        int r = slot >> 4, nn = slot & 15;
        u32 d0 = (u32)lds_x[0 * 1088 + r * 17 + nn + 1] | ((u32)lds_x[1 * 1088 + r * 17 + nn + 1] << 16);
        u32 d1 = (u32)lds_x[2 * 1088 + r * 17 + nn + 1];
        u32 d2 = (u32)lds_x[0 * 1088 + r * 17 + nn]     | ((u32)lds_x[1 * 1088 + r * 17 + nn] << 16);
        u32 d3 = (u32)lds_x[2 * 1088 + r * 17 + nn];
        *(uint4*)(lds_xpk + slot * 16) = make_uint4(d0, d1, d2, d3);
    }
    __syncthreads();

    // bias -> registers (this wave's two gates)
    f32x4 bias_r[2];
    #pragma unroll
    for (int gg = 0; gg < 2; ++gg) {
        int oc = (gbase + gg) * 128 + p * 16 + q * 4;
        bias_r[gg][0] = lds_bias[oc + 0];
        bias_r[gg][1] = lds_bias[oc + 1];
        bias_r[gg][2] = lds_bias[oc + 2];
        bias_r[gg][3] = lds_bias[oc + 3];
    }

    // consumer pipeline state (tid<32 = front wave 0 lanes, s>0 blocks)
    u64 hv = 0, hn = 0;
    const bool is_cons = (s > 0) && (tid < 32);
    if (is_cons)
        hv = __hip_atomic_load((const u64*)(hs_up + (size_t)tid * 8),
                               __ATOMIC_RELAXED, __HIP_MEMORY_SCOPE_AGENT);

    // ================= row loop: ONE relaxed barrier per row =================
    for (int r = 0; r < 64; ++r) {
        char* rbuf = lds_buf + (r & 1) * BUFBYTES;
        char* wbuf = lds_buf + ((r & 1) ^ 1) * BUFBYTES;

        // ---- top: prefetch halo slot r+1 (validated at row r+1 bottom) ----
        if (is_cons && r < 62)
            hn = __hip_atomic_load((const u64*)(hs_up + (size_t)(r + 1) * 256 + tid * 8),
                                   __ATOMIC_RELAXED, __HIP_MEMORY_SCOPE_AGENT);

        // ---- batch all 9 B-tile reads (lgkm overlaps acc-init + MFMAs) ----
        bf16x8 bv[9];
        #pragma unroll
        for (int kt = 0; kt < 8; ++kt)
            bv[kt] = *(const bf16x8*)(rbuf + LINE(kt, lane));
        bv[8] = *(const bf16x8*)(lds_xpk + r * 256 + n * 16);  // quad-broadcast

        // ---- GEMM: this wave's two gate tiles ----
        f32x4 acc[2];
        acc[0] = bias_r[0]; acc[1] = bias_r[1];
        #pragma unroll
        for (int kt = 0; kt < 9; ++kt) {
            acc[0] = __builtin_amdgcn_mfma_f32_16x16x32_bf16(afr[0][kt], bv[kt], acc[0], 0, 0, 0);
            acc[1] = __builtin_amdgcn_mfma_f32_16x16x32_bf16(afr[1][kt], bv[kt], acc[1], 0, 0, 0);
        }

        if (!front) {
            // ---- back: ig = sig(i)*sig(g) = rcp(t + eg*t), t = 1+ei ----
            f32x4 igv;
            #pragma unroll
            for (int reg = 0; reg < 4; ++reg) {
                float ei = __expf(-acc[0][reg]);
                float eg = __expf(-acc[1][reg]);
                float t  = 1.0f + ei;
                igv[reg] = __builtin_amdgcn_rcpf(__builtin_fmaf(eg, t, t));
            }
            *(f32x4*)(lds_igb + (p * 64 + lane) * 16) = igv;
            // publish: drain LDS write, then monotone flag = r+1
            __builtin_amdgcn_sched_barrier(0);
            asm volatile("s_waitcnt lgkmcnt(0)" ::: "memory");
            __builtin_amdgcn_sched_barrier(0);
            if (lane == 0)
                __hip_atomic_store(&igf[p], (u32)(r + 1), __ATOMIC_RELAXED,
                                   __HIP_MEMORY_SCOPE_WORKGROUP);
        } else {
            // ---- front: receive ig (usually already published) ----
            u32 fv = __hip_atomic_load(&igf[p], __ATOMIC_RELAXED,
                                       __HIP_MEMORY_SCOPE_WORKGROUP);
            if (fv < (u32)(r + 1)) {
                int guard = 0;
                do {
                    __builtin_amdgcn_s_sleep(1);
                    fv = __hip_atomic_load(&igf[p], __ATOMIC_RELAXED,
                                           __HIP_MEMORY_SCOPE_WORKGROUP);
                } while (fv < (u32)(r + 1) && ++guard < SPIN_CAP);
            }
            // forbid hoisting the ig read above the flag observation
            int igo = (p * 64 + lane) * 16;
            asm volatile("" : "+v"(igo) : "v"(fv));
            f32x4 ig4 = *(const f32x4*)(lds_igb + igo);

            // ---- EW: o,f gates + recurrence (math identical to r9) ----
            float hval[4];
            #pragma unroll
            for (int reg = 0; reg < 4; ++reg) {
                float eo = __expf(-acc[0][reg]);
                float ef = __expf(-acc[1][reg]);
                float f_ = __builtin_amdgcn_rcpf(1.0f + ef);
                float cn = f_ * cst[reg] + ig4[reg];
                cst[reg] = cn;
                float o_ = __builtin_amdgcn_rcpf(1.0f + eo);
                float e2 = __expf(2.0f * cn);
                float th = 1.0f - 2.0f * __builtin_amdgcn_rcpf(e2 + 1.0f);
                hval[reg] = o_ * th;
            }

            // ---- pack h pairs with v_cvt_pk_bf16_f32 (RNE = f2b bit-exact) ----
            u32 plo, phi;
            asm("v_cvt_pk_bf16_f32 %0, %1, %2" : "=v"(plo) : "v"(hval[0]), "v"(hval[1]));
            asm("v_cvt_pk_bf16_f32 %0, %1, %2" : "=v"(phi) : "v"(hval[2]), "v"(hval[3]));
            u64 d01 = (u64)plo | ((u64)phi << 32);

            // ---- h -> LDS (wbuf); edge lanes fire inverted halo word ----
            *(u64*)(wbuf + LINE(p, lane)) = d01;               // tap1 halves
            int wl = n + 1;
            if (wl < 16) {
                *(u64*)(wbuf + LINE(p, q * 16 + wl) + 8) = d01;
            } else if (s < 3 && r < 63) {
                // fire-and-forget: ~data (nonzero for all finite h) = valid
                __hip_atomic_store((u64*)(hs_my + (size_t)r * 256 + (p * 4 + q) * 8),
                                   ~d01, __ATOMIC_RELAXED, __HIP_MEMORY_SCOPE_AGENT);
            }

            // ---- out stores (fire-and-forget; never waited on) ----
            #pragma unroll
            for (int reg = 0; reg < 4; ++reg) {
                int hc = p * 16 + q * 4 + reg;
                out[(((size_t)(b * 128 + hc)) * 64 + r) * 64 + wbase + n] = hval[reg];
            }

            // ---- consumer: validate + commit slot r (loaded row r-1 top) ----
            if (is_cons && r < 63) {
                if (hv == 0) {
                    int guard = 0;
                    do {
                        __builtin_amdgcn_s_sleep(1);           // fill only
                        hv = __hip_atomic_load((const u64*)(hs_up + (size_t)r * 256 + tid * 8),
                                               __ATOMIC_RELAXED, __HIP_MEMORY_SCOPE_AGENT);
                    } while (hv == 0 && ++guard < SPIN_CAP);
                }
                *(u64*)(wbuf + LINE(tid >> 2, (tid & 3) * 16) + 8) = ~hv;
                hv = hn;
            }
        }

        // ---- relaxed barrier: order LDS only (no vmem drain) ----
        __builtin_amdgcn_sched_barrier(0);
        asm volatile("s_waitcnt lgkmcnt(0)\n\ts_barrier" ::: "memory");
        __builtin_amdgcn_sched_barrier(0);
    }
}

extern "C" void kernel_launch(void* const* d_in, const int* in_sizes, int n_in,
                              void* d_out, int out_size, void* d_ws, size_t ws_size,
                              hipStream_t stream)
{
    const float* x   = (const float*)d_in[0];
    const float* Wis = (const float*)d_in[1];
    const float* bis = (const float*)d_in[2];
    const float* Wss = (const float*)d_in[3];
    const float* bss = (const float*)d_in[4];
    const float* h0  = (const float*)d_in[5];
    const float* c0  = (const float*)d_in[6];
    float* out = (float*)d_out;

    // halo: 32 b x 4 s x 64 r x 256 B = 2 MB, write-once inverted words.
    // Must be zeroed every launch (word!=0 is the valid bit).
    hipMemsetAsync(d_ws, 0, (size_t)32 * 4 * 64 * 256, stream);
    rowlstm_mfma14<<<dim3(4, 32), 1024, 0, stream>>>(
        x, Wis, bis, Wss, bss, h0, c0, out, (char*)d_ws);
}

// Round 11
// 202.715 us; speedup vs baseline: 1.1113x; 1.1113x over previous
//
#include <hip/hip_runtime.h>
#include <hip/hip_bf16.h>

typedef unsigned short u16;
typedef unsigned int u32;
typedef unsigned long long u64;
typedef short bf16x8 __attribute__((ext_vector_type(8)));
typedef float f32x4  __attribute__((ext_vector_type(4)));

// RowLSTM B=32, Cin=3, H=W=64, HC=128, gates o,f,i,g (all sigmoid), c=f*c+i*g,
// h=o*tanh(c). Masked-B 1x3 conv: taps (w-1, w).
//
// Round 18: r9 base (127.5us best; r10 gate-split regressed 19% -- handshake
// in the serial chain) + the two last in-structure levers:
//  1) trans diet 9->8 per reg: h = (e2-1)*rcp((e2+1)*(1+eo)) merges the o-
//     sigmoid and tanh denominators into ONE rcp. NaN-guard: cc=fmin(cn,15)
//     before e2 (tanh(15)==1.0f in fp32 -> exact; prevents e2=inf -> inf*0).
//     Trans floor of this algebra: 5 exp + 3 rcp = 8/reg.
//  2) LDS line-swizzle line' = line ^ (line>>3) on lds_buf, applied at EVERY
//     write AND read (h tap1/tap0 writes, h0 init, halo commit, bv reads).
//     Within-line layout untouched -> MFMA K-mapping legal (per-(q,j) K slots
//     identical across lanes). Targets SQ_LDS_BANK_CONFLICT=716800/dispatch
//     (~87cy/row/block): consumer-commit was 32 lanes -> 1 bank (32-way).
// Everything else identical to r9: x_pk precompute, inverted-word halo (2MB
// ws, memset per launch), relaxed lgkmcnt-only barrier, capped spins,
// cvt_pk packing, batched bv reads.

__device__ __forceinline__ u16 f2b(float f) {
    return __builtin_bit_cast(u16, __float2bfloat16(f));
}

#define SWZ(l) ((l) ^ ((l) >> 3))
#define BUFBYTES (8 * 64 * 16)   /* 8192 B per buffer (tiles 0..7) */
#define SPIN_CAP (1 << 16)

__global__ __launch_bounds__(512, 2) void rowlstm_mfma15(
    const float* __restrict__ x,   const float* __restrict__ Wis,
    const float* __restrict__ bis, const float* __restrict__ Wss,
    const float* __restrict__ bss, const float* __restrict__ h0,
    const float* __restrict__ c0,  float* __restrict__ out,
    char* halo)
{
    __shared__ __align__(16) char lds_buf[2 * BUFBYTES];   // 16384 B
    __shared__ __align__(16) char lds_xpk[64 * 16 * 16];   // 16384 B (x K-tiles)
    __shared__ u16  lds_x[3 * 64 * 17];                    // 6528 B
    __shared__ float lds_bias[512];                        // 2048 B

    const int tid  = threadIdx.x;
    const int s    = blockIdx.x;            // w-quarter
    const int b    = blockIdx.y;            // batch
    const int wid  = tid >> 6;              // wave [0,8) = hc-tile
    const int lane = tid & 63;
    const int q    = lane >> 4;             // quad
    const int n    = lane & 15;             // w within quarter
    const int wbase = s * 16;

    // swizzled line offsets (loop-invariant)
    const int slb  = SWZ(lane) * 16;                    // own line byte offset
    const int wl   = n + 1;
    const int tln  = q * 16 + (wl & 15);
    const int stb  = SWZ(tln) * 16;                     // shifted-target line
    const int clq  = (tid & 3) * 16;                    // commit line (tid<32)
    const int scb  = SWZ(clq) * 16;

    // halo slot: per (b,s,r): 32 units x 8B = 256B; unit u holds ~[4xbf16 h]
    // for ic = u*4..u*4+3 of the right-edge column. word!=0 <=> valid.
    char* hs_my = halo + ((size_t)(b * 4 + s) * 64) * 256;
    char* hs_up = halo + ((size_t)(b * 4 + (s > 0 ? s - 1 : 0)) * 64) * 256;

    // ---------- phase 0: zero both B buffers ----------
    for (int i = tid; i < 1024; i += 512)
        *(uint4*)(lds_buf + i * 16) = make_uint4(0, 0, 0, 0);
    __syncthreads();

    // ---------- phase 1: one-time staging ----------
    lds_bias[tid] = bis[tid] + bss[tid];

    // x -> LDS bf16: [cch][r][wl1], wl1 = local w + 1 (col 0 = left halo col)
    for (int i = tid; i < 3264; i += 512) {
        int cch = i / 1088, rem = i % 1088;
        int r = rem / 17, wl1 = rem % 17;
        int gw = wbase + wl1 - 1;
        lds_x[i] = (gw < 0) ? (u16)0
                 : f2b(x[(((size_t)b * 3 + cch) * 64 + r) * 64 + gw]);
    }

    // A-fragments (persist in regs): a[j]=tap1(ic=kt*16+q*4+j), a[4+j]=tap0
    bf16x8 afr[4][9];
    {
        #pragma unroll
        for (int g = 0; g < 4; ++g) {
            int oc = g * 128 + wid * 16 + n;           // m = n
            #pragma unroll
            for (int kt = 0; kt < 8; ++kt) {
                bf16x8 a;
                #pragma unroll
                for (int jj = 0; jj < 4; ++jj) {
                    int ic = kt * 16 + q * 4 + jj;
                    float2 wp = *(const float2*)&Wss[(size_t)(oc * 128 + ic) * 3];
                    a[jj]     = (short)f2b(wp.y);      // tap1 (center)
                    a[4 + jj] = (short)f2b(wp.x);      // tap0 (left)
                }
                afr[g][kt] = a;
            }
            bf16x8 ax = {0, 0, 0, 0, 0, 0, 0, 0};
            if (q == 0) {
                #pragma unroll
                for (int cch = 0; cch < 3; ++cch) {
                    float2 wp = *(const float2*)&Wis[(size_t)(oc * 3 + cch) * 3];
                    ax[cch]     = (short)f2b(wp.y);
                    ax[4 + cch] = (short)f2b(wp.x);
                }
            }
            afr[g][8] = ax;
        }
    }

    // c-state (fp32, registers) + h0 publish into buf0 (swizzled lines)
    float cst[4];
    {
        u16 hw[4];
        #pragma unroll
        for (int reg = 0; reg < 4; ++reg) {
            int hc = wid * 16 + q * 4 + reg;
            int wg = wbase + n;
            cst[reg] = c0[hc * 64 + wg];
            hw[reg] = f2b(h0[hc * 64 + wg]);
        }
        u64 d01 = (u64)((u32)hw[0] | ((u32)hw[1] << 16))
                | ((u64)((u32)hw[2] | ((u32)hw[3] << 16)) << 32);
        *(u64*)(lds_buf + wid * 1024 + slb) = d01;              // tap1 halves
        if (wl < 16)
            *(u64*)(lds_buf + wid * 1024 + stb + 8) = d01;
    }
    // s>0: left-edge tap0 column from h0[:, wbase-1] (h0 is known globally)
    if (s > 0 && tid < 32) {
        int ic0 = tid * 4;
        u64 v = (u64)((u32)f2b(h0[(ic0 + 0) * 64 + wbase - 1]) | ((u32)f2b(h0[(ic0 + 1) * 64 + wbase - 1]) << 16))
              | ((u64)((u32)f2b(h0[(ic0 + 2) * 64 + wbase - 1]) | ((u32)f2b(h0[(ic0 + 3) * 64 + wbase - 1]) << 16)) << 32);
        *(u64*)(lds_buf + (tid >> 2) * 1024 + scb + 8) = v;
    }

    // ensure lds_x fully written before packing x_pk
    __syncthreads();

    // x_pk[r][n] 16B = packed x K-tile value for (row r, col n)
    #pragma unroll
    for (int t = 0; t < 2; ++t) {
        int slot = tid + t * 512;
        int r = slot >> 4, nn = slot & 15;
        u32 d0 = (u32)lds_x[0 * 1088 + r * 17 + nn + 1] | ((u32)lds_x[1 * 1088 + r * 17 + nn + 1] << 16);
        u32 d1 = (u32)lds_x[2 * 1088 + r * 17 + nn + 1];
        u32 d2 = (u32)lds_x[0 * 1088 + r * 17 + nn]     | ((u32)lds_x[1 * 1088 + r * 17 + nn] << 16);
        u32 d3 = (u32)lds_x[2 * 1088 + r * 17 + nn];
        *(uint4*)(lds_xpk + slot * 16) = make_uint4(d0, d1, d2, d3);
    }
    __syncthreads();

    // bias -> registers (constant per lane across rows)
    f32x4 bias_r[4];
    #pragma unroll
    for (int g = 0; g < 4; ++g) {
        int oc = g * 128 + wid * 16 + q * 4;
        bias_r[g][0] = lds_bias[oc + 0];
        bias_r[g][1] = lds_bias[oc + 1];
        bias_r[g][2] = lds_bias[oc + 2];
        bias_r[g][3] = lds_bias[oc + 3];
    }

    // consumer pipeline state (tid<32 of s>0 blocks)
    u64 hv = 0, hn = 0;
    const bool is_cons = (s > 0) && (tid < 32);
    if (is_cons)
        hv = __hip_atomic_load((const u64*)(hs_up + (size_t)tid * 8),
                               __ATOMIC_RELAXED, __HIP_MEMORY_SCOPE_AGENT);

    // ================= row loop: ONE relaxed barrier per row =================
    for (int r = 0; r < 64; ++r) {
        char* rbuf = lds_buf + (r & 1) * BUFBYTES;
        char* wbuf = lds_buf + ((r & 1) ^ 1) * BUFBYTES;

        // ---- top: prefetch halo slot r+1 (validated at row r+1 bottom) ----
        if (is_cons && r < 62)
            hn = __hip_atomic_load((const u64*)(hs_up + (size_t)(r + 1) * 256 + tid * 8),
                                   __ATOMIC_RELAXED, __HIP_MEMORY_SCOPE_AGENT);

        // ---- batch all 9 B-tile reads (lgkm overlaps acc-init + MFMAs) ----
        bf16x8 bv[9];
        #pragma unroll
        for (int kt = 0; kt < 8; ++kt)
            bv[kt] = *(const bf16x8*)(rbuf + kt * 1024 + slb);
        bv[8] = *(const bf16x8*)(lds_xpk + r * 256 + n * 16);  // quad-broadcast

        // ---- GEMM ----
        f32x4 acc[4];
        acc[0] = bias_r[0]; acc[1] = bias_r[1];
        acc[2] = bias_r[2]; acc[3] = bias_r[3];
        #pragma unroll
        for (int kt = 0; kt < 9; ++kt) {
            acc[0] = __builtin_amdgcn_mfma_f32_16x16x32_bf16(afr[0][kt], bv[kt], acc[0], 0, 0, 0);
            acc[1] = __builtin_amdgcn_mfma_f32_16x16x32_bf16(afr[1][kt], bv[kt], acc[1], 0, 0, 0);
            acc[2] = __builtin_amdgcn_mfma_f32_16x16x32_bf16(afr[2][kt], bv[kt], acc[2], 0, 0, 0);
            acc[3] = __builtin_amdgcn_mfma_f32_16x16x32_bf16(afr[3][kt], bv[kt], acc[3], 0, 0, 0);
        }

        // ---- elementwise: 8 trans/reg (5 exp + 3 rcp) ----
        // ig = sig(i)*sig(g) = rcp(t + eg*t), t = 1+ei
        // h  = sig(o)*tanh(c) = (e2-1) * rcp((e2+1)*(1+eo)), e2 = exp(2*min(c,15))
        // fmin clamp is EXACT (tanh(15)==1.0f in fp32) and kills the inf*0 path.
        float hval[4];
        #pragma unroll
        for (int reg = 0; reg < 4; ++reg) {
            float eo = __expf(-acc[0][reg]);
            float ef = __expf(-acc[1][reg]);
            float ei = __expf(-acc[2][reg]);
            float eg = __expf(-acc[3][reg]);
            float f_ = __builtin_amdgcn_rcpf(1.0f + ef);
            float t  = 1.0f + ei;
            float ig = __builtin_amdgcn_rcpf(__builtin_fmaf(eg, t, t));
            float cn = f_ * cst[reg] + ig;
            cst[reg] = cn;
            float cc = fminf(cn, 15.0f);
            float e2 = __expf(2.0f * cc);
            float dq = (e2 + 1.0f) * (1.0f + eo);
            hval[reg] = (e2 - 1.0f) * __builtin_amdgcn_rcpf(dq);
        }

        // ---- pack h pairs with v_cvt_pk_bf16_f32 (RNE = f2b bit-exact) ----
        u32 plo, phi;
        asm("v_cvt_pk_bf16_f32 %0, %1, %2" : "=v"(plo) : "v"(hval[0]), "v"(hval[1]));
        asm("v_cvt_pk_bf16_f32 %0, %1, %2" : "=v"(phi) : "v"(hval[2]), "v"(hval[3]));
        u64 d01 = (u64)plo | ((u64)phi << 32);

        // ---- h -> LDS (wbuf, swizzled); edge lanes fire inverted halo word ----
        *(u64*)(wbuf + wid * 1024 + slb) = d01;                // tap1 halves
        if (wl < 16) {
            *(u64*)(wbuf + wid * 1024 + stb + 8) = d01;
        } else if (s < 3 && r < 63) {
            // fire-and-forget: ~data (nonzero for all finite h) = valid
            __hip_atomic_store((u64*)(hs_my + (size_t)r * 256 + (wid * 4 + q) * 8),
                               ~d01, __ATOMIC_RELAXED, __HIP_MEMORY_SCOPE_AGENT);
        }

        // ---- out stores (fire-and-forget; never waited on) ----
        #pragma unroll
        for (int reg = 0; reg < 4; ++reg) {
            int hc = wid * 16 + q * 4 + reg;
            out[(((size_t)(b * 128 + hc)) * 64 + r) * 64 + wbase + n] = hval[reg];
        }

        // ---- consumer: validate + commit slot r (loaded at row r-1 top) ----
        if (is_cons && r < 63) {
            if (hv == 0) {
                int guard = 0;
                do {
                    __builtin_amdgcn_s_sleep(1);               // fill only
                    hv = __hip_atomic_load((const u64*)(hs_up + (size_t)r * 256 + tid * 8),
                                           __ATOMIC_RELAXED, __HIP_MEMORY_SCOPE_AGENT);
                } while (hv == 0 && ++guard < SPIN_CAP);
            }
            *(u64*)(wbuf + (tid >> 2) * 1024 + scb + 8) = ~hv;
            hv = hn;
        }

        // ---- relaxed barrier: order LDS only (no vmem drain) ----
        __builtin_amdgcn_sched_barrier(0);
        asm volatile("s_waitcnt lgkmcnt(0)\n\ts_barrier" ::: "memory");
        __builtin_amdgcn_sched_barrier(0);
    }
}

extern "C" void kernel_launch(void* const* d_in, const int* in_sizes, int n_in,
                              void* d_out, int out_size, void* d_ws, size_t ws_size,
                              hipStream_t stream)
{
    const float* x   = (const float*)d_in[0];
    const float* Wis = (const float*)d_in[1];
    const float* bis = (const float*)d_in[2];
    const float* Wss = (const float*)d_in[3];
    const float* bss = (const float*)d_in[4];
    const float* h0  = (const float*)d_in[5];
    const float* c0  = (const float*)d_in[6];
    float* out = (float*)d_out;

    // halo: 32 b x 4 s x 64 r x 256 B = 2 MB, write-once inverted words.
    // Must be zeroed every launch (word!=0 is the valid bit).
    hipMemsetAsync(d_ws, 0, (size_t)32 * 4 * 64 * 256, stream);
    rowlstm_mfma15<<<dim3(4, 32), 512, 0, stream>>>(
        x, Wis, bis, Wss, bss, h0, c0, out, (char*)d_ws);
}

// Round 12
// 198.821 us; speedup vs baseline: 1.1331x; 1.0196x over previous
//
#include <hip/hip_runtime.h>
#include <hip/hip_bf16.h>

typedef unsigned short u16;
typedef unsigned int u32;
typedef unsigned long long u64;
typedef short bf16x8 __attribute__((ext_vector_type(8)));
typedef float f32x4  __attribute__((ext_vector_type(4)));

// RowLSTM B=32, Cin=3, H=W=64, HC=128, gates o,f,i,g (all sigmoid), c=f*c+i*g,
// h=o*tanh(c). Masked-B 1x3 conv: taps (w-1, w).
//
// Round 19: r11 base (127.8us; trans diet + LDS swizzle kept -- conflicts
// -21%, time null => latency-floor confirmed) + SINGLE-ROW HALO COVER.
// The consumer now loads halo slot r at row r TOP and validates/commits at
// row r bottom (cover = 1 full row ~2us >> ~0.9us cross-XCD latency), instead
// of prefetching 2 rows ahead. This cuts the required inter-stage skew from
// ~2 rows to ~1 row => saves ~1 row x 3 stages of pipeline fill/drain tail
// (~4-6us of the s=3 block's finish time), and drops the hn double-buffer +
// one global load/row on the consumer wave. Self-stabilizing: a miss spins
// once at commit, pushing the stage's skew up -- worst case equals today.
// Everything else identical to r11: x_pk precompute, inverted-word halo (2MB
// ws, memset per launch), relaxed lgkmcnt-only barrier, capped spins, cvt_pk
// packing, batched bv reads, 8-trans EW, lds_buf line-swizzle.

__device__ __forceinline__ u16 f2b(float f) {
    return __builtin_bit_cast(u16, __float2bfloat16(f));
}

#define SWZ(l) ((l) ^ ((l) >> 3))
#define BUFBYTES (8 * 64 * 16)   /* 8192 B per buffer (tiles 0..7) */
#define SPIN_CAP (1 << 16)

__global__ __launch_bounds__(512, 2) void rowlstm_mfma16(
    const float* __restrict__ x,   const float* __restrict__ Wis,
    const float* __restrict__ bis, const float* __restrict__ Wss,
    const float* __restrict__ bss, const float* __restrict__ h0,
    const float* __restrict__ c0,  float* __restrict__ out,
    char* halo)
{
    __shared__ __align__(16) char lds_buf[2 * BUFBYTES];   // 16384 B
    __shared__ __align__(16) char lds_xpk[64 * 16 * 16];   // 16384 B (x K-tiles)
    __shared__ u16  lds_x[3 * 64 * 17];                    // 6528 B
    __shared__ float lds_bias[512];                        // 2048 B

    const int tid  = threadIdx.x;
    const int s    = blockIdx.x;            // w-quarter
    const int b    = blockIdx.y;            // batch
    const int wid  = tid >> 6;              // wave [0,8) = hc-tile
    const int lane = tid & 63;
    const int q    = lane >> 4;             // quad
    const int n    = lane & 15;             // w within quarter
    const int wbase = s * 16;

    // swizzled line offsets (loop-invariant)
    const int slb  = SWZ(lane) * 16;                    // own line byte offset
    const int wl   = n + 1;
    const int tln  = q * 16 + (wl & 15);
    const int stb  = SWZ(tln) * 16;                     // shifted-target line
    const int clq  = (tid & 3) * 16;                    // commit line (tid<32)
    const int scb  = SWZ(clq) * 16;

    // halo slot: per (b,s,r): 32 units x 8B = 256B; unit u holds ~[4xbf16 h]
    // for ic = u*4..u*4+3 of the right-edge column. word!=0 <=> valid.
    char* hs_my = halo + ((size_t)(b * 4 + s) * 64) * 256;
    char* hs_up = halo + ((size_t)(b * 4 + (s > 0 ? s - 1 : 0)) * 64) * 256;

    // ---------- phase 0: zero both B buffers ----------
    for (int i = tid; i < 1024; i += 512)
        *(uint4*)(lds_buf + i * 16) = make_uint4(0, 0, 0, 0);
    __syncthreads();

    // ---------- phase 1: one-time staging ----------
    lds_bias[tid] = bis[tid] + bss[tid];

    // x -> LDS bf16: [cch][r][wl1], wl1 = local w + 1 (col 0 = left halo col)
    for (int i = tid; i < 3264; i += 512) {
        int cch = i / 1088, rem = i % 1088;
        int r = rem / 17, wl1 = rem % 17;
        int gw = wbase + wl1 - 1;
        lds_x[i] = (gw < 0) ? (u16)0
                 : f2b(x[(((size_t)b * 3 + cch) * 64 + r) * 64 + gw]);
    }

    // A-fragments (persist in regs): a[j]=tap1(ic=kt*16+q*4+j), a[4+j]=tap0
    bf16x8 afr[4][9];
    {
        #pragma unroll
        for (int g = 0; g < 4; ++g) {
            int oc = g * 128 + wid * 16 + n;           // m = n
            #pragma unroll
            for (int kt = 0; kt < 8; ++kt) {
                bf16x8 a;
                #pragma unroll
                for (int jj = 0; jj < 4; ++jj) {
                    int ic = kt * 16 + q * 4 + jj;
                    float2 wp = *(const float2*)&Wss[(size_t)(oc * 128 + ic) * 3];
                    a[jj]     = (short)f2b(wp.y);      // tap1 (center)
                    a[4 + jj] = (short)f2b(wp.x);      // tap0 (left)
                }
                afr[g][kt] = a;
            }
            bf16x8 ax = {0, 0, 0, 0, 0, 0, 0, 0};
            if (q == 0) {
                #pragma unroll
                for (int cch = 0; cch < 3; ++cch) {
                    float2 wp = *(const float2*)&Wis[(size_t)(oc * 3 + cch) * 3];
                    ax[cch]     = (short)f2b(wp.y);
                    ax[4 + cch] = (short)f2b(wp.x);
                }
            }
            afr[g][8] = ax;
        }
    }

    // c-state (fp32, registers) + h0 publish into buf0 (swizzled lines)
    float cst[4];
    {
        u16 hw[4];
        #pragma unroll
        for (int reg = 0; reg < 4; ++reg) {
            int hc = wid * 16 + q * 4 + reg;
            int wg = wbase + n;
            cst[reg] = c0[hc * 64 + wg];
            hw[reg] = f2b(h0[hc * 64 + wg]);
        }
        u64 d01 = (u64)((u32)hw[0] | ((u32)hw[1] << 16))
                | ((u64)((u32)hw[2] | ((u32)hw[3] << 16)) << 32);
        *(u64*)(lds_buf + wid * 1024 + slb) = d01;              // tap1 halves
        if (wl < 16)
            *(u64*)(lds_buf + wid * 1024 + stb + 8) = d01;
    }
    // s>0: left-edge tap0 column from h0[:, wbase-1] (h0 is known globally)
    if (s > 0 && tid < 32) {
        int ic0 = tid * 4;
        u64 v = (u64)((u32)f2b(h0[(ic0 + 0) * 64 + wbase - 1]) | ((u32)f2b(h0[(ic0 + 1) * 64 + wbase - 1]) << 16))
              | ((u64)((u32)f2b(h0[(ic0 + 2) * 64 + wbase - 1]) | ((u32)f2b(h0[(ic0 + 3) * 64 + wbase - 1]) << 16)) << 32);
        *(u64*)(lds_buf + (tid >> 2) * 1024 + scb + 8) = v;
    }

    // ensure lds_x fully written before packing x_pk
    __syncthreads();

    // x_pk[r][n] 16B = packed x K-tile value for (row r, col n)
    #pragma unroll
    for (int t = 0; t < 2; ++t) {
        int slot = tid + t * 512;
        int r = slot >> 4, nn = slot & 15;
        u32 d0 = (u32)lds_x[0 * 1088 + r * 17 + nn + 1] | ((u32)lds_x[1 * 1088 + r * 17 + nn + 1] << 16);
        u32 d1 = (u32)lds_x[2 * 1088 + r * 17 + nn + 1];
        u32 d2 = (u32)lds_x[0 * 1088 + r * 17 + nn]     | ((u32)lds_x[1 * 1088 + r * 17 + nn] << 16);
        u32 d3 = (u32)lds_x[2 * 1088 + r * 17 + nn];
        *(uint4*)(lds_xpk + slot * 16) = make_uint4(d0, d1, d2, d3);
    }
    __syncthreads();

    // bias -> registers (constant per lane across rows)
    f32x4 bias_r[4];
    #pragma unroll
    for (int g = 0; g < 4; ++g) {
        int oc = g * 128 + wid * 16 + q * 4;
        bias_r[g][0] = lds_bias[oc + 0];
        bias_r[g][1] = lds_bias[oc + 1];
        bias_r[g][2] = lds_bias[oc + 2];
        bias_r[g][3] = lds_bias[oc + 3];
    }

    const bool is_cons = (s > 0) && (tid < 32);
    u64 hv = 0;

    // ================= row loop: ONE relaxed barrier per row =================
    for (int r = 0; r < 64; ++r) {
        char* rbuf = lds_buf + (r & 1) * BUFBYTES;
        char* wbuf = lds_buf + ((r & 1) ^ 1) * BUFBYTES;

        // ---- top: load halo slot r (single-row cover; validated at bottom) ----
        if (is_cons && r < 63)
            hv = __hip_atomic_load((const u64*)(hs_up + (size_t)r * 256 + tid * 8),
                                   __ATOMIC_RELAXED, __HIP_MEMORY_SCOPE_AGENT);

        // ---- batch all 9 B-tile reads (lgkm overlaps acc-init + MFMAs) ----
        bf16x8 bv[9];
        #pragma unroll
        for (int kt = 0; kt < 8; ++kt)
            bv[kt] = *(const bf16x8*)(rbuf + kt * 1024 + slb);
        bv[8] = *(const bf16x8*)(lds_xpk + r * 256 + n * 16);  // quad-broadcast

        // ---- GEMM ----
        f32x4 acc[4];
        acc[0] = bias_r[0]; acc[1] = bias_r[1];
        acc[2] = bias_r[2]; acc[3] = bias_r[3];
        #pragma unroll
        for (int kt = 0; kt < 9; ++kt) {
            acc[0] = __builtin_amdgcn_mfma_f32_16x16x32_bf16(afr[0][kt], bv[kt], acc[0], 0, 0, 0);
            acc[1] = __builtin_amdgcn_mfma_f32_16x16x32_bf16(afr[1][kt], bv[kt], acc[1], 0, 0, 0);
            acc[2] = __builtin_amdgcn_mfma_f32_16x16x32_bf16(afr[2][kt], bv[kt], acc[2], 0, 0, 0);
            acc[3] = __builtin_amdgcn_mfma_f32_16x16x32_bf16(afr[3][kt], bv[kt], acc[3], 0, 0, 0);
        }

        // ---- elementwise: 8 trans/reg (5 exp + 3 rcp) ----
        // ig = sig(i)*sig(g) = rcp(t + eg*t), t = 1+ei
        // h  = sig(o)*tanh(c) = (e2-1) * rcp((e2+1)*(1+eo)), e2 = exp(2*min(c,15))
        // fmin clamp is EXACT (tanh(15)==1.0f in fp32) and kills the inf*0 path.
        float hval[4];
        #pragma unroll
        for (int reg = 0; reg < 4; ++reg) {
            float eo = __expf(-acc[0][reg]);
            float ef = __expf(-acc[1][reg]);
            float ei = __expf(-acc[2][reg]);
            float eg = __expf(-acc[3][reg]);
            float f_ = __builtin_amdgcn_rcpf(1.0f + ef);
            float t  = 1.0f + ei;
            float ig = __builtin_amdgcn_rcpf(__builtin_fmaf(eg, t, t));
            float cn = f_ * cst[reg] + ig;
            cst[reg] = cn;
            float cc = fminf(cn, 15.0f);
            float e2 = __expf(2.0f * cc);
            float dq = (e2 + 1.0f) * (1.0f + eo);
            hval[reg] = (e2 - 1.0f) * __builtin_amdgcn_rcpf(dq);
        }

        // ---- pack h pairs with v_cvt_pk_bf16_f32 (RNE = f2b bit-exact) ----
        u32 plo, phi;
        asm("v_cvt_pk_bf16_f32 %0, %1, %2" : "=v"(plo) : "v"(hval[0]), "v"(hval[1]));
        asm("v_cvt_pk_bf16_f32 %0, %1, %2" : "=v"(phi) : "v"(hval[2]), "v"(hval[3]));
        u64 d01 = (u64)plo | ((u64)phi << 32);

        // ---- h -> LDS (wbuf, swizzled); edge lanes fire inverted halo word ----
        *(u64*)(wbuf + wid * 1024 + slb) = d01;                // tap1 halves
        if (wl < 16) {
            *(u64*)(wbuf + wid * 1024 + stb + 8) = d01;
        } else if (s < 3 && r < 63) {
            // fire-and-forget: ~data (nonzero for all finite h) = valid
            __hip_atomic_store((u64*)(hs_my + (size_t)r * 256 + (wid * 4 + q) * 8),
                               ~d01, __ATOMIC_RELAXED, __HIP_MEMORY_SCOPE_AGENT);
        }

        // ---- out stores (fire-and-forget; never waited on) ----
        #pragma unroll
        for (int reg = 0; reg < 4; ++reg) {
            int hc = wid * 16 + q * 4 + reg;
            out[(((size_t)(b * 128 + hc)) * 64 + r) * 64 + wbase + n] = hval[reg];
        }

        // ---- consumer: validate + commit slot r (loaded at row r top) ----
        if (is_cons && r < 63) {
            if (hv == 0) {
                int guard = 0;
                do {
                    __builtin_amdgcn_s_sleep(1);               // fill only
                    hv = __hip_atomic_load((const u64*)(hs_up + (size_t)r * 256 + tid * 8),
                                           __ATOMIC_RELAXED, __HIP_MEMORY_SCOPE_AGENT);
                } while (hv == 0 && ++guard < SPIN_CAP);
            }
            *(u64*)(wbuf + (tid >> 2) * 1024 + scb + 8) = ~hv;
        }

        // ---- relaxed barrier: order LDS only (no vmem drain) ----
        __builtin_amdgcn_sched_barrier(0);
        asm volatile("s_waitcnt lgkmcnt(0)\n\ts_barrier" ::: "memory");
        __builtin_amdgcn_sched_barrier(0);
    }
}

extern "C" void kernel_launch(void* const* d_in, const int* in_sizes, int n_in,
                              void* d_out, int out_size, void* d_ws, size_t ws_size,
                              hipStream_t stream)
{
    const float* x   = (const float*)d_in[0];
    const float* Wis = (const float*)d_in[1];
    const float* bis = (const float*)d_in[2];
    const float* Wss = (const float*)d_in[3];
    const float* bss = (const float*)d_in[4];
    const float* h0  = (const float*)d_in[5];
    const float* c0  = (const float*)d_in[6];
    float* out = (float*)d_out;

    // halo: 32 b x 4 s x 64 r x 256 B = 2 MB, write-once inverted words.
    // Must be zeroed every launch (word!=0 is the valid bit).
    hipMemsetAsync(d_ws, 0, (size_t)32 * 4 * 64 * 256, stream);
    rowlstm_mfma16<<<dim3(4, 32), 512, 0, stream>>>(
        x, Wis, bis, Wss, bss, h0, c0, out, (char*)d_ws);
}